// Round 14
// baseline (259.724 us; speedup 1.0000x reference)
//
#include <hip/hip_runtime.h>

// SelfAttention_Pseudoformer: B=8, L=2048, C=512, P=64, H=8, DK=64
// Outputs (f32, concat): z [B,L,C], pScore(masked) [B,L,P], scores [B,H,L,P]

typedef __attribute__((ext_vector_type(8))) short bhalf8;   // 8 bf16 (4 VGPR)
typedef __attribute__((ext_vector_type(4))) float fx4;      // MFMA acc frag

__device__ __forceinline__ unsigned short f2bf(float f) {
  union { float f; unsigned u; } v; v.f = f;
  unsigned u = v.u + 0x7fffu + ((v.u >> 16) & 1u);          // RNE
  return (unsigned short)(u >> 16);
}
__device__ __forceinline__ float bf2f(unsigned short h) {
  union { unsigned u; float f; } v; v.u = ((unsigned)h) << 16;
  return v.f;
}
__device__ __forceinline__ void gld16(const void* g, void* l) {
  __builtin_amdgcn_global_load_lds(
      (const __attribute__((address_space(1))) void*)g,
      (__attribute__((address_space(3))) void*)l, 16, 0, 0);
}

// ---------------------------------------------------------------------------
// bf16 MFMA GEMM body:  C[r,c] = sum_k A[r,k] * BT[c,k]  (+bias[c])
// AF32: 0 = A bf16 (gld16); 1 = A f32 reg-staged cvt; 2 = A = pbuf 4-chunk sum
// BF32: 0 = B bf16 (gld16); 1 = B from f32 [K][N] Bf32 (ldbt=N, strided);
//       2 = B from batched f32 (h ? Bf32b : Bf32) + b*LC, [K][N] strided (ldbt=N)
// KSPLIT: byy = K-chunk index (row0=0, K=chunk len, C += y*sCk).
// CMODE: 0 f32 | 1 bf16 | 2 bf16 vpT-scatter | 3 f32 masked pScore -> ps_out (NT)
//        + pScoreT via LDS transpose (coalesced) | 4 merged K/V-proj | 5 f32 NT
// ---------------------------------------------------------------------------
template <int BM, int BN, int CMODE, int AF32, int KSPLIT, int BF32>
__device__ __forceinline__ void gemm_body(
    int bxx, int byy, int bzz, char* smemc,
    const void* __restrict__ Av, const unsigned short* __restrict__ BT,
    const float* __restrict__ bias, void* __restrict__ Cout,
    int K, int lda, int ldbt, int ldc, int HDIV,
    long sAb, long sAh, long sBb, long sBh, long sCb, long sCh, long sCk,
    const int* __restrict__ mpad, float* __restrict__ aux,
    const float* __restrict__ Bf32, const float* __restrict__ Bf32b)
{
  constexpr int NA = BM / 16, NB = BN / 16, NT = NA + NB;
  constexpr int WM = BM / 2, WN = BN / 2, FM = WM / 16, FN = WN / 16;
  unsigned short* lds = (unsigned short*)smemc;
  const int t = threadIdx.x, l = t & 63, w = t >> 6;
  const int wr = w >> 1, wc = w & 1;
  const int zz = bzz, b = zz / HDIV, h = zz % HDIV;
  const int row0 = KSPLIT ? 0 : byy * BM;
  const int koff = KSPLIT ? byy * K : 0;
  const long cko = KSPLIT ? (long)byy * sCk : 0;
  const int col0 = bxx * BN;
  const unsigned short* Ag = (const unsigned short*)Av + b * sAb + h * sAh + (long)row0 * lda + koff;
  const float* AgF = (const float*)Av + b * sAb + h * sAh + (long)row0 * lda + koff;
  const unsigned short* Bg = BT + b * sBb + h * sBh + (long)col0 * ldbt + koff;
  const int lr = l & 15, lc = l >> 4;

  fx4 acc[FM][FN];
#pragma unroll
  for (int i = 0; i < FM; ++i)
#pragma unroll
    for (int j = 0; j < FN; ++j) acc[i][j] = fx4{0.f, 0.f, 0.f, 0.f};

  for (int k0 = 0; k0 < K; k0 += 32) {
#pragma unroll
    for (int i = 0; i < NT / 4; ++i) {
      const int tile = w + i * 4;
      if (tile < NA) {                                   // ---- A tile
        if constexpr (AF32 == 1) {
          const float* gf = AgF + (long)(tile * 16 + lr) * lda + k0 + lc * 8;
          float4 x = *(const float4*)gf, y = *(const float4*)(gf + 4);
          bhalf8 pk;
          pk[0] = (short)f2bf(x.x); pk[1] = (short)f2bf(x.y);
          pk[2] = (short)f2bf(x.z); pk[3] = (short)f2bf(x.w);
          pk[4] = (short)f2bf(y.x); pk[5] = (short)f2bf(y.y);
          pk[6] = (short)f2bf(y.z); pk[7] = (short)f2bf(y.w);
          *(bhalf8*)&lds[tile * 512 + l * 8] = pk;
        } else if constexpr (AF32 == 2) {
          const float* gf = (const float*)Av + (long)zz * sAb + (long)byy * 131072
                            + (long)(tile * 16 + lr) * 512 + k0 + lc * 8;
          float4 x = make_float4(0.f, 0.f, 0.f, 0.f), y = x;
#pragma unroll
          for (int c = 0; c < 4; ++c) {
            float4 a = *(const float4*)(gf + (long)c * 32768);
            float4 bq = *(const float4*)(gf + (long)c * 32768 + 4);
            x.x += a.x; x.y += a.y; x.z += a.z; x.w += a.w;
            y.x += bq.x; y.y += bq.y; y.z += bq.z; y.w += bq.w;
          }
          bhalf8 pk;
          pk[0] = (short)f2bf(x.x); pk[1] = (short)f2bf(x.y);
          pk[2] = (short)f2bf(x.z); pk[3] = (short)f2bf(x.w);
          pk[4] = (short)f2bf(y.x); pk[5] = (short)f2bf(y.y);
          pk[6] = (short)f2bf(y.z); pk[7] = (short)f2bf(y.w);
          *(bhalf8*)&lds[tile * 512 + l * 8] = pk;
        } else {
          gld16(Ag + (long)(tile * 16 + lr) * lda + k0 + lc * 8, &lds[tile * 512]);
        }
      } else {                                           // ---- B tile
        if constexpr (BF32 == 1) {
          const int ct = tile - NA;
          const float* gfB = Bf32 + (long)(koff + k0 + lc * 8) * ldbt + col0 + ct * 16 + lr;
          bhalf8 pk;
#pragma unroll
          for (int i2 = 0; i2 < 8; ++i2) pk[i2] = (short)f2bf(gfB[(long)i2 * ldbt]);
          *(bhalf8*)&lds[tile * 512 + l * 8] = pk;
        } else if constexpr (BF32 == 2) {
          const int ct = tile - NA;
          const float* src = (h ? Bf32b : Bf32) + (long)b * 1048576
                             + (long)(koff + k0 + lc * 8) * ldbt + col0 + ct * 16 + lr;
          bhalf8 pk;
#pragma unroll
          for (int i2 = 0; i2 < 8; ++i2) pk[i2] = (short)f2bf(src[(long)i2 * ldbt]);
          *(bhalf8*)&lds[tile * 512 + l * 8] = pk;
        } else {
          gld16(Bg + (long)((tile - NA) * 16 + lr) * ldbt + k0 + lc * 8, &lds[tile * 512]);
        }
      }
    }
    __syncthreads();
    bhalf8 af[FM], bf[FN];
#pragma unroll
    for (int i = 0; i < FM; ++i) af[i] = *(const bhalf8*)&lds[(wr * FM + i) * 512 + l * 8];
#pragma unroll
    for (int j = 0; j < FN; ++j) bf[j] = *(const bhalf8*)&lds[(NA + wc * FN + j) * 512 + l * 8];
#pragma unroll
    for (int i = 0; i < FM; ++i)
#pragma unroll
      for (int j = 0; j < FN; ++j)
        acc[i][j] = __builtin_amdgcn_mfma_f32_16x16x32_bf16(af[i], bf[j], acc[i][j], 0, 0, 0);
    __syncthreads();
  }

  if constexpr (CMODE == 3) {
    float (*tbuf)[65] = (float(*)[65])(smemc + NT * 1024);
#pragma unroll
    for (int fm = 0; fm < FM; ++fm) {
#pragma unroll
      for (int fn = 0; fn < FN; ++fn) {
        const int rg0 = row0 + wr * WM + fm * 16 + lc * 4;
        const int cg = col0 + wc * WN + fn * 16 + lr;
        const float bb = bias[cg];
#pragma unroll
        for (int jj = 0; jj < 4; ++jj) {
          const int rg = rg0 + jj;
          float vv = acc[fm][fn][jj] + bb;
          if (mpad[((long)(rg >> 11)) * (2048L * 2048) + (rg & 2047)] == 0) vv = -32768.f;
          __builtin_nontemporal_store(vv, (float*)Cout + (long)rg * ldc + cg);
          tbuf[rg - row0][cg] = vv;
        }
      }
    }
    __syncthreads();
    const int b0 = row0 >> 11, l0b = row0 & 2047;
    const int pp = t >> 2, li0 = (t & 3) * 16;
    float* dst = aux + ((long)b0 * 64 + pp) * 2048 + l0b + li0;
#pragma unroll
    for (int i = 0; i < 16; i += 4) {
      float4 o = make_float4(tbuf[li0 + i][pp],     tbuf[li0 + i + 1][pp],
                             tbuf[li0 + i + 2][pp], tbuf[li0 + i + 3][pp]);
      *(float4*)(dst + i) = o;
    }
  } else {
#pragma unroll
    for (int fm = 0; fm < FM; ++fm) {
#pragma unroll
      for (int fn = 0; fn < FN; ++fn) {
        const int rg0 = row0 + wr * WM + fm * 16 + lc * 4;
        const int cg = col0 + wc * WN + fn * 16 + lr;
        float bb = 0.f;
        if constexpr (CMODE == 4) {
          bb = (zz == 0) ? bias[cg] : ((const float*)mpad)[cg];
        } else {
          bb = bias ? bias[cg] : 0.f;
        }
#pragma unroll
        for (int jj = 0; jj < 4; ++jj) {
          const int rg = rg0 + jj;
          const float v = acc[fm][fn][jj] + bb;
          if constexpr (CMODE == 0) {
            ((float*)Cout)[b * sCb + h * sCh + cko + (long)rg * ldc + cg] = v;
          } else if constexpr (CMODE == 1) {
            ((unsigned short*)Cout)[b * sCb + h * sCh + (long)rg * ldc + cg] = f2bf(v);
          } else if constexpr (CMODE == 2) {
            ((unsigned short*)Cout)[(((long)(rg >> 6) * 8 + (cg >> 6)) * 64 + (cg & 63)) * 64 + (rg & 63)] = f2bf(v);
          } else if constexpr (CMODE == 4) {       // merged K/V-proj
            if (zz == 0)
              ((unsigned short*)Cout)[(long)rg * ldc + cg] = f2bf(v);
            else
              ((unsigned short*)Cout)[262144 + (((long)(rg >> 6) * 8 + (cg >> 6)) * 64 + (cg & 63)) * 64 + (rg & 63)] = f2bf(v);
          } else {                                 // CMODE 5: f32 nontemporal
            __builtin_nontemporal_store(v, (float*)Cout + b * sCb + h * sCh + cko + (long)rg * ldc + cg);
          }
        }
      }
    }
  }
}

template <int BM, int BN, int CMODE, int AF32, int KSPLIT>
__global__ __launch_bounds__(256)
void gemm_mfma(const void* __restrict__ Av, const unsigned short* __restrict__ BT,
               const float* __restrict__ bias, void* __restrict__ Cout,
               int K, int lda, int ldbt, int ldc, int HDIV,
               long sAb, long sAh, long sBb, long sBh, long sCb, long sCh, long sCk,
               const int* __restrict__ mpad, float* __restrict__ aux)
{
  constexpr int SM = (BM / 16 + BN / 16) * 1024 + (CMODE == 3 ? 16640 : 0);
  __shared__ __align__(16) char smem[SM];
  gemm_body<BM, BN, CMODE, AF32, KSPLIT, 0>(blockIdx.x, blockIdx.y, blockIdx.z, smem,
      Av, BT, bias, Cout, K, lda, ldbt, ldc, HDIV,
      sAb, sAh, sBb, sBh, sCb, sCh, sCk, mpad, aux, nullptr, nullptr);
}

// ---------------------------------------------------------------------------
// transpose body: in [R][Cd] f32 tile at (r0,c0) -> out [Cd][R] bf16
// ---------------------------------------------------------------------------
__device__ __forceinline__ void tr_body(float (*tile)[65], const float* __restrict__ in,
                                        unsigned short* __restrict__ out,
                                        int R, int Cd, int r0, int c0, int t)
{
  const int tr = t >> 4, tc4 = (t & 15) * 4;
#pragma unroll
  for (int pass = 0; pass < 4; ++pass) {
    int r = pass * 16 + tr;
    float4 v = *(const float4*)(in + (long)(r0 + r) * Cd + c0 + tc4);
    tile[r][tc4] = v.x; tile[r][tc4 + 1] = v.y; tile[r][tc4 + 2] = v.z; tile[r][tc4 + 3] = v.w;
  }
  __syncthreads();
#pragma unroll
  for (int pass = 0; pass < 4; ++pass) {
    int c = pass * 16 + tr;
    ushort4 o;
    o.x = f2bf(tile[tc4][c]);     o.y = f2bf(tile[tc4 + 1][c]);
    o.z = f2bf(tile[tc4 + 2][c]); o.w = f2bf(tile[tc4 + 3][c]);
    *(ushort4*)(out + (long)(c0 + c) * R + r0 + tc4) = o;
  }
}

// ---------------------------------------------------------------------------
// combo0: flat grid 512 blocks.
//  [0,256):   pScore GEMM (A=vx f32, B=Wp f32 strided) -> ps_out NT + pScoreT
//  [256,512): Wq/Wk/Wv/Wo transposes (4 x 64 tiles)
// ---------------------------------------------------------------------------
__global__ __launch_bounds__(256)
void combo0(const float* __restrict__ vx, const float* __restrict__ Wp,
            const float* __restrict__ bp, const int* __restrict__ maskPAD,
            float* __restrict__ ps_out, float* __restrict__ pScoreT,
            const float* __restrict__ Wq, const float* __restrict__ Wk,
            const float* __restrict__ Wv, const float* __restrict__ Wo,
            unsigned short* __restrict__ WqT, unsigned short* __restrict__ WkT,
            unsigned short* __restrict__ WvT, unsigned short* __restrict__ WoT)
{
  __shared__ __align__(16) char smem[24832];
  const int id = blockIdx.x;
  if (id < 256) {
    gemm_body<64, 64, 3, 1, 0, 1>(0, id, 0, smem,
        vx, nullptr, bp, ps_out, 512, 512, 64, 64, 1,
        0, 0, 0, 0, 0, 0, 0, maskPAD, pScoreT, Wp, nullptr);
  } else {
    const int r = id - 256;
    const int z = r >> 6, rem = r & 63;
    const float* in; unsigned short* out;
    switch (z) {
      case 0: in = Wq; out = WqT; break;
      case 1: in = Wk; out = WkT; break;
      case 2: in = Wv; out = WvT; break;
      default: in = Wo; out = WoT; break;
    }
    tr_body((float(*)[65])smem, in, out, 512, 512, (rem >> 3) * 64, (rem & 7) * 64, threadIdx.x);
  }
}

// ---------------------------------------------------------------------------
// kb body (global-read, r7-style): (Kt,Bt) per (b,h,l,p) from PST [B,L,64] bf16.
// Lane = p -> every sample read is a coalesced 128B line, all L2-resident (2MB).
// 4 l-values per thread; grid 128 x 8 = 1024 sub-blocks (short tail).
// ---------------------------------------------------------------------------
__device__ __forceinline__ void kb_body(int bx, int by, char* smemc,
    const unsigned short* __restrict__ PST,
    const float* __restrict__ embK, const float* __restrict__ embB,
    ushort2* __restrict__ KB)
{
  const int L = 2048;
  float (*eKs)[8] = (float(*)[8])smemc;
  float (*eBs)[8] = (float(*)[8])(smemc + 512);
  const int t = threadIdx.x, b = by, l0 = bx * 16;
  if (t < 128) {
    int r = t >> 3, h = t & 7;
    eKs[r][h] = (r < 15) ? embK[r * 8 + h] : 0.f;
    eBs[r][h] = (r < 15) ? embB[r * 8 + h] : 0.f;
  }
  __syncthreads();
  const int p = t & 63, lw = t >> 6;
  const int Btab[14] = {0,1,2,3,4,5,6,8,10,14,22,38,70,134};
  const unsigned short* pst = PST + (long)b * L * 64 + p;
  const float u2047 = bf2f(pst[(long)(L - 1) * 64]);
#pragma unroll
  for (int il = 0; il < 4; ++il) {
    const int l = l0 + lw * 4 + il;
    float U[15];
#pragma unroll
    for (int r = 0; r < 14; ++r) {
      int hi = l + Btab[r]; hi = hi > L - 1 ? L - 1 : hi;
      float u = bf2f(pst[(long)hi * 64]);
      const int lo = l - 1 - Btab[r];
      if (lo >= 0) u -= bf2f(pst[(long)lo * 64]);
      U[r] = u;
    }
    U[14] = u2047;                                       // hi clamps to L-1, lo < 0
    for (int h = 0; h < 8; ++h) {
      float Kt = 0.f, Bt = 0.f;
#pragma unroll
      for (int r = 0; r < 15; ++r) {
        Kt = fmaf(eKs[r][h] - eKs[r + 1][h], U[r], Kt);
        Bt = fmaf(eBs[r][h] - eBs[r + 1][h], U[r], Bt);
      }
      ushort2 o; o.x = f2bf(Kt); o.y = f2bf(Bt);
      KB[(((long)(b * 8 + h)) * L + l) * 64 + p] = o;
    }
  }
}

// combo1: blocks 0..511 -> split-K kxc/vxc GEMM partials (B direct from f32
// kx/vx via BF32=2); 512..1535 -> kb table (1024 small blocks). LDS 8KB only.
__global__ __launch_bounds__(256)
void combo1(const unsigned short* __restrict__ pAbf,
            const float* __restrict__ kx, const float* __restrict__ vx,
            float* __restrict__ pbuf,
            const unsigned short* __restrict__ PST,
            const float* __restrict__ embK, const float* __restrict__ embB,
            ushort2* __restrict__ KB)
{
  __shared__ __align__(16) char smem[8192];
  const int id = blockIdx.x;
  if (id < 512) {
    gemm_body<64, 64, 0, 0, 1, 2>(id & 7, (id >> 3) & 3, id >> 5, smem,
        pAbf, nullptr, nullptr, pbuf, 512, 2048, 512, 512, 2,
        131072, 0, 0, 0, 131072, 1048576, 32768, nullptr, nullptr, kx, vx);
  } else {
    const int r = id - 512;
    kb_body(r & 127, r >> 7, smem, PST, embK, embB, KB);
  }
}

// combo2: blocks 0..63 -> merged K/V-proj (A = pbuf 4-sum); 64..575 -> Q-proj.
__global__ __launch_bounds__(256)
void combo2(const float* __restrict__ pbuf, const unsigned short* __restrict__ WkT,
            const float* __restrict__ bk, const float* __restrict__ bv,
            unsigned short* __restrict__ kp,
            const float* __restrict__ qx, const unsigned short* __restrict__ WqT,
            const float* __restrict__ bq, unsigned short* __restrict__ qbf)
{
  __shared__ __align__(16) char smem[16384];
  const int id = blockIdx.x;
  if (id < 64) {
    gemm_body<64, 128, 4, 2, 0, 0>(id & 3, (id >> 2) & 7, id >> 5, smem,
        pbuf, WkT, bk, kp, 512, 512, 512, 512, 1,
        1048576, 0, 262144, 0, 0, 0, 0, (const int*)bv, nullptr, nullptr, nullptr);
  } else {
    const int r = id - 64;
    gemm_body<128, 128, 1, 1, 0, 0>(r & 3, r >> 2, 0, smem,
        qx, WqT, bq, qbf, 512, 512, 512, 512, 1,
        0, 0, 0, 0, 0, 0, 0, nullptr, nullptr, nullptr, nullptr);
  }
}

// ---------------------------------------------------------------------------
// softmax over L per (b,p) + normalized inclusive prefix scan (coalesced reads).
// Writes PST bf16 [B,L,P] (scattered 2B, L2-absorbed) and pAlphaT bf16 [B,P,L].
// ---------------------------------------------------------------------------
__global__ __launch_bounds__(256)
void softmax_scan(const float* __restrict__ pScoreT,
                  unsigned short* __restrict__ PST, unsigned short* __restrict__ pA_bf)
{
  __shared__ float red[256];
  const int p = blockIdx.x, b = blockIdx.y, t = threadIdx.x;
  const float* row = pScoreT + ((size_t)b * 64 + p) * 2048;
  float4 va = ((const float4*)row)[t * 2], vb = ((const float4*)row)[t * 2 + 1];
  float v[8] = {va.x, va.y, va.z, va.w, vb.x, vb.y, vb.z, vb.w};
  float mx = v[0];
#pragma unroll
  for (int i = 1; i < 8; ++i) mx = fmaxf(mx, v[i]);
  red[t] = mx; __syncthreads();
  for (int s = 128; s > 0; s >>= 1) { if (t < s) red[t] = fmaxf(red[t], red[t + s]); __syncthreads(); }
  float m = red[0]; __syncthreads();
  float e[8]; float s = 0.f;
#pragma unroll
  for (int i = 0; i < 8; ++i) { e[i] = expf(v[i] - m); s += e[i]; }
  red[t] = s; __syncthreads();
  for (int o = 1; o < 256; o <<= 1) {
    float x = (t >= o) ? red[t - o] : 0.f;
    __syncthreads(); red[t] += x; __syncthreads();
  }
  float inv = 1.0f / red[255];
  float run = red[t] - s;
  size_t baseA = ((size_t)b * 64 + p) * 2048 + (size_t)t * 8;     // pAbf [B,P,L]
  size_t baseT = ((size_t)b * 2048 + (size_t)t * 8) * 64 + p;     // PST  [B,L,P]
#pragma unroll
  for (int i = 0; i < 8; ++i) {
    run += e[i];
    PST[baseT + (size_t)i * 64] = f2bf(run * inv);
    pA_bf[baseA + i] = f2bf(e[i] * inv);
  }
}

// ---------------------------------------------------------------------------
// Fused attention with XCD-bijective block swizzle; KB prefetched to registers.
// ---------------------------------------------------------------------------
__global__ __launch_bounds__(256)
void attn_fused(const unsigned short* __restrict__ qb,   // [B,L,512] bf16
                const unsigned short* __restrict__ kp,   // [B,64,512] bf16
                const unsigned short* __restrict__ vpT,  // [B,H,64,64] bf16
                const ushort2* __restrict__ KB,          // [B,H,L,64] (Kt,Bt)
                float* __restrict__ sc_out,              // [B,H,L,64] f32
                unsigned short* __restrict__ zpre)       // [B,L,512] bf16
{
  const int L = 2048;
  __shared__ __align__(16) unsigned short stg[24 * 512]; // q 0..15, kp 16..23; V reuses 0..7
  unsigned short* qkb = &stg[8 * 512];                   // qk/alpha overlays tiles 8..23
  const int t = threadIdx.x, l = t & 63, w = t >> 6, lr = l & 15, lc = l >> 4;
  const int flat = blockIdx.y * 16 + blockIdx.x;
  const int swz = (flat & 7) * 128 + (flat >> 3);
  const int z = swz >> 4, b = z >> 3, h = z & 7;
  const int l0 = (swz & 15) * 128;
  const unsigned short* Ag = qb + ((long)(b * L + l0)) * 512 + h * 64;
  const unsigned short* Bg = kp + (long)b * 64 * 512 + h * 64;
#pragma unroll
  for (int i = 0; i < 6; ++i) {                          // stage q (16 tiles) + kp (8)
    const int tile = w + i * 4;
    const unsigned short* g;
    if (tile < 16) { int rt = tile >> 1, ks = tile & 1; g = Ag + (long)(rt * 16 + lr) * 512 + ks * 32 + lc * 8; }
    else { int j = tile - 16; int rt = j >> 1, ks = j & 1; g = Bg + (long)(rt * 16 + lr) * 512 + ks * 32 + lc * 8; }
    gld16(g, &stg[tile * 512]);
  }
  const ushort2* kbb = KB + (((long)(b * 8 + h)) * L + l0) * 64 + l;
  unsigned int kbreg[32];
#pragma unroll
  for (int i = 0; i < 32; ++i)
    kbreg[i] = *(const unsigned int*)(kbb + ((long)(w * 32 + i)) * 64);
  __syncthreads();
  // ---- phase 1: QK MFMA (2x2 waves, WM=64, WN=32, FM=4, FN=2)
  const int wr = w >> 1, wc = w & 1;
  fx4 acc[4][2];
#pragma unroll
  for (int i = 0; i < 4; ++i)
#pragma unroll
    for (int j = 0; j < 2; ++j) acc[i][j] = fx4{0.f, 0.f, 0.f, 0.f};
#pragma unroll
  for (int ks = 0; ks < 2; ++ks) {
    bhalf8 af[4], bf[2];
#pragma unroll
    for (int i = 0; i < 4; ++i) af[i] = *(const bhalf8*)&stg[((wr * 4 + i) * 2 + ks) * 512 + l * 8];
#pragma unroll
    for (int j = 0; j < 2; ++j) bf[j] = *(const bhalf8*)&stg[(16 + (wc * 2 + j) * 2 + ks) * 512 + l * 8];
#pragma unroll
    for (int i = 0; i < 4; ++i)
#pragma unroll
      for (int j = 0; j < 2; ++j)
        acc[i][j] = __builtin_amdgcn_mfma_f32_16x16x32_bf16(af[i], bf[j], acc[i][j], 0, 0, 0);
  }
  __syncthreads();                                       // q/kp tiles dead -> qk overlays
#pragma unroll
  for (int fm = 0; fm < 4; ++fm)
#pragma unroll
    for (int fn = 0; fn < 2; ++fn)
#pragma unroll
      for (int jj = 0; jj < 4; ++jj) {
        const int row = wr * 64 + fm * 16 + lc * 4 + jj;
        const int col = wc * 32 + fn * 16 + lr;
        *(unsigned short*)((char*)qkb + ((row * 128 + col * 2) ^ ((row & 7) << 4))) = f2bf(acc[fm][fn][jj]);
      }
  __syncthreads();
  // stage V (8 tiles into stg 0..7), overlapping phase 2
  {
    const unsigned short* Vg = vpT + ((long)(b * 8 + h)) * 64 * 64;
#pragma unroll
    for (int i = 0; i < 2; ++i) {
      const int tile = w + i * 4, rt = tile >> 1, ks = tile & 1;
      gld16(Vg + (long)(rt * 16 + lr) * 64 + ks * 32 + lc * 8, &stg[tile * 512]);
    }
  }
  // ---- phase 2: scores from KB regs + softmax_P (wave w rows w*32..+31, lane = p)
  const int p = l;
  float* scb = sc_out + ((long)(b * 8 + h) * L + l0) * 64 + p;
#pragma unroll
  for (int c = 0; c < 8; ++c) {
    const int rbase = w * 32 + c * 4;
    float sv[4];
#pragma unroll
    for (int il = 0; il < 4; ++il) {
      const int row = rbase + il;
      const unsigned int kbw = kbreg[c * 4 + il];
      const float qkv = bf2f(*(const unsigned short*)((const char*)qkb + ((row * 128 + p * 2) ^ ((row & 7) << 4))));
      sv[il] = qkv * 0.125f * bf2f((unsigned short)(kbw & 0xffffu)) + bf2f((unsigned short)(kbw >> 16));
      __builtin_nontemporal_store(sv[il], scb + (long)row * 64);
    }
    float mx[4] = {sv[0], sv[1], sv[2], sv[3]};
#pragma unroll
    for (int o = 32; o > 0; o >>= 1)
#pragma unroll
      for (int il = 0; il < 4; ++il) mx[il] = fmaxf(mx[il], __shfl_xor(mx[il], o, 64));
    float ex[4], sm[4];
#pragma unroll
    for (int il = 0; il < 4; ++il) { ex[il] = __expf(sv[il] - mx[il]); sm[il] = ex[il]; }
#pragma unroll
    for (int o = 32; o > 0; o >>= 1)
#pragma unroll
      for (int il = 0; il < 4; ++il) sm[il] += __shfl_xor(sm[il], o, 64);
#pragma unroll
    for (int il = 0; il < 4; ++il) {
      const int row = rbase + il;
      *(unsigned short*)((char*)qkb + ((row * 128 + p * 2) ^ ((row & 7) << 4))) = f2bf(ex[il] / sm[il]);
    }
  }
  __syncthreads();
  // ---- phase 3: PV MFMA (A = alpha LDS swizzled, B = V tiles 0..7)
  fx4 a2[4][2];
#pragma unroll
  for (int i = 0; i < 4; ++i)
#pragma unroll
    for (int j = 0; j < 2; ++j) a2[i][j] = fx4{0.f, 0.f, 0.f, 0.f};
#pragma unroll
  for (int ks = 0; ks < 2; ++ks) {
    bhalf8 paf[4], pvf[2];
#pragma unroll
    for (int i = 0; i < 4; ++i) {
      const int row = (wr * 4 + i) * 16 + lr;
      paf[i] = *(const bhalf8*)((const char*)qkb + ((row * 128 + ks * 64 + lc * 16) ^ ((row & 7) << 4)));
    }
#pragma unroll
    for (int j = 0; j < 2; ++j)
      pvf[j] = *(const bhalf8*)&stg[(((wc * 2 + j) * 2 + ks) * 512) + l * 8];
#pragma unroll
    for (int i = 0; i < 4; ++i)
#pragma unroll
      for (int j = 0; j < 2; ++j)
        a2[i][j] = __builtin_amdgcn_mfma_f32_16x16x32_bf16(paf[i], pvf[j], a2[i][j], 0, 0, 0);
  }
#pragma unroll
  for (int fm = 0; fm < 4; ++fm)
#pragma unroll
    for (int fn = 0; fn < 2; ++fn)
#pragma unroll
      for (int jj = 0; jj < 4; ++jj) {
        const int row = wr * 64 + fm * 16 + lc * 4 + jj;
        const int col = wc * 32 + fn * 16 + lr;
        zpre[((long)(b * L + l0 + row)) * 512 + h * 64 + col] = f2bf(a2[fm][fn][jj]);
      }
}

// ---------------------------------------------------------------------------
extern "C" void kernel_launch(void* const* d_in, const int* in_sizes, int n_in,
                              void* d_out, int out_size, void* d_ws, size_t ws_size,
                              hipStream_t stream)
{
  const int B = 8, L = 2048, C = 512, P = 64;
  const float* qx = (const float*)d_in[0];
  const float* kx = (const float*)d_in[1];
  const float* vx = (const float*)d_in[2];
  const int* maskPAD = (const int*)d_in[3];
  const float* Wp = (const float*)d_in[4];
  const float* bp = (const float*)d_in[5];
  const float* Wq = (const float*)d_in[6];
  const float* bq = (const float*)d_in[7];
  const float* Wk = (const float*)d_in[8];
  const float* bk = (const float*)d_in[9];
  const float* Wv = (const float*)d_in[10];
  const float* bv = (const float*)d_in[11];
  const float* Wo = (const float*)d_in[12];
  const float* bo = (const float*)d_in[13];
  const float* embK = (const float*)d_in[14];
  const float* embB = (const float*)d_in[15];

  float* z_out  = (float*)d_out;                         // [B,L,C]
  float* ps_out = z_out + (size_t)B * L * C;             // [B,L,P]
  float* sc_out = ps_out + (size_t)B * L * P;            // [B,H,L,P]

  char* w8 = (char*)d_ws;
  size_t o = 0;
  auto take = [&](size_t n) { char* r = w8 + o; o += n; return r; };
  unsigned short* R_A  = (unsigned short*)take(16777216); // zpre [B,L,512]
  unsigned short* R_B  = (unsigned short*)take(16777216); // q_bf [B,L,512]
  unsigned short* WqT  = (unsigned short*)take(524288);
  unsigned short* WkT  = (unsigned short*)take(524288);
  unsigned short* WvT  = (unsigned short*)take(524288);
  unsigned short* WoT  = (unsigned short*)take(524288);
  float* pScoreT       = (float*)take(4194304);          // [B,P,L] f32 (masked)
  unsigned short* PST  = (unsigned short*)take(2097152); // [B,L,P] bf16 prefix
  unsigned short* pAbf = (unsigned short*)take(2097152); // [B,P,L] bf16
  float* pbuf          = (float*)take(8388608);          // [2][8][4][32768]
  unsigned short* kp   = (unsigned short*)take(1048576); // kp then vpT (contiguous)
  ushort2* KB          = (ushort2*)take(33554432);       // [B,H,L,64] (Kt,Bt) bf16

  // 1) combo0: pScore GEMM (input-only) || weight transposes
  combo0<<<dim3(512), 256, 0, stream>>>(
      vx, Wp, bp, maskPAD, ps_out, pScoreT,
      Wq, Wk, Wv, Wo, WqT, WkT, WvT, WoT);
  // 2) softmax_L + prefix scan -> PST bf16 [B,L,P], pAbf bf16 [B,P,L]
  softmax_scan<<<dim3(P, B), 256, 0, stream>>>(pScoreT, PST, pAbf);
  // 3) combo1: split-K kxc/vxc partials (B direct from kx/vx) || KB table (1024)
  combo1<<<dim3(1536), 256, 0, stream>>>(pAbf, kx, vx, pbuf, PST, embK, embB, KB);
  // 4) combo2: merged K/V-proj from pbuf (64 blocks) || Q-proj (512 blocks)
  combo2<<<dim3(576), 256, 0, stream>>>(pbuf, WkT, bk, bv, kp, qx, WqT, bq, R_B);
  // 5) fused attention: scores (NT f32) + softmax + PV -> zpre
  attn_fused<<<dim3(16, 64), 256, 0, stream>>>(
      R_B, kp, kp + 262144, KB, sc_out, R_A);
  // 6) z = zpre @ Wo + bo (NT f32)
  gemm_mfma<128, 128, 5, 0, 0><<<dim3(4, 128, 1), 256, 0, stream>>>(
      R_A, WoT, bo, z_out, 512, 512, 512, 512, 1, 0, 0, 0, 0, 0, 0, 0, nullptr, nullptr);
}

// Round 15
// 198.185 us; speedup vs baseline: 1.3105x; 1.3105x over previous
//
#include <hip/hip_runtime.h>

// SelfAttention_Pseudoformer: B=8, L=2048, C=512, P=64, H=8, DK=64
// Outputs (f32, concat): z [B,L,C], pScore(masked) [B,L,P], scores [B,H,L,P]

typedef __attribute__((ext_vector_type(8))) short bhalf8;   // 8 bf16 (4 VGPR)
typedef __attribute__((ext_vector_type(4))) float fx4;      // MFMA acc frag

__device__ __forceinline__ unsigned short f2bf(float f) {
  union { float f; unsigned u; } v; v.f = f;
  unsigned u = v.u + 0x7fffu + ((v.u >> 16) & 1u);          // RNE
  return (unsigned short)(u >> 16);
}
__device__ __forceinline__ float bf2f(unsigned short h) {
  union { unsigned u; float f; } v; v.u = ((unsigned)h) << 16;
  return v.f;
}
__device__ __forceinline__ void gld16(const void* g, void* l) {
  __builtin_amdgcn_global_load_lds(
      (const __attribute__((address_space(1))) void*)g,
      (__attribute__((address_space(3))) void*)l, 16, 0, 0);
}

// ---------------------------------------------------------------------------
// bf16 MFMA GEMM body:  C[r,c] = sum_k A[r,k] * BT[c,k]  (+bias[c])
// AF32: 0 = A bf16 (gld16); 1 = A f32 reg-staged cvt; 2 = A = pbuf 4-chunk sum
// BF32: 0 = B bf16 (gld16); 1 = B from f32 [K][N] Bf32 (ldbt=N, strided);
//       2 = B from batched f32 (h ? Bf32b : Bf32) + b*LC, [K][N] strided (ldbt=N)
// KSPLIT: byy = K-chunk index (row0=0, K=chunk len, C += y*sCk).
// CMODE: 0 f32 | 1 bf16 | 2 bf16 vpT-scatter | 3 f32 masked pScore -> ps_out (NT)
//        + pScoreT via LDS transpose (coalesced) | 4 merged K/V-proj | 5 f32 NT
// ---------------------------------------------------------------------------
template <int BM, int BN, int CMODE, int AF32, int KSPLIT, int BF32>
__device__ __forceinline__ void gemm_body(
    int bxx, int byy, int bzz, char* smemc,
    const void* __restrict__ Av, const unsigned short* __restrict__ BT,
    const float* __restrict__ bias, void* __restrict__ Cout,
    int K, int lda, int ldbt, int ldc, int HDIV,
    long sAb, long sAh, long sBb, long sBh, long sCb, long sCh, long sCk,
    const int* __restrict__ mpad, float* __restrict__ aux,
    const float* __restrict__ Bf32, const float* __restrict__ Bf32b)
{
  constexpr int NA = BM / 16, NB = BN / 16, NT = NA + NB;
  constexpr int WM = BM / 2, WN = BN / 2, FM = WM / 16, FN = WN / 16;
  unsigned short* lds = (unsigned short*)smemc;
  const int t = threadIdx.x, l = t & 63, w = t >> 6;
  const int wr = w >> 1, wc = w & 1;
  const int zz = bzz, b = zz / HDIV, h = zz % HDIV;
  const int row0 = KSPLIT ? 0 : byy * BM;
  const int koff = KSPLIT ? byy * K : 0;
  const long cko = KSPLIT ? (long)byy * sCk : 0;
  const int col0 = bxx * BN;
  const unsigned short* Ag = (const unsigned short*)Av + b * sAb + h * sAh + (long)row0 * lda + koff;
  const float* AgF = (const float*)Av + b * sAb + h * sAh + (long)row0 * lda + koff;
  const unsigned short* Bg = BT + b * sBb + h * sBh + (long)col0 * ldbt + koff;
  const int lr = l & 15, lc = l >> 4;

  fx4 acc[FM][FN];
#pragma unroll
  for (int i = 0; i < FM; ++i)
#pragma unroll
    for (int j = 0; j < FN; ++j) acc[i][j] = fx4{0.f, 0.f, 0.f, 0.f};

  for (int k0 = 0; k0 < K; k0 += 32) {
#pragma unroll
    for (int i = 0; i < NT / 4; ++i) {
      const int tile = w + i * 4;
      if (tile < NA) {                                   // ---- A tile
        if constexpr (AF32 == 1) {
          const float* gf = AgF + (long)(tile * 16 + lr) * lda + k0 + lc * 8;
          float4 x = *(const float4*)gf, y = *(const float4*)(gf + 4);
          bhalf8 pk;
          pk[0] = (short)f2bf(x.x); pk[1] = (short)f2bf(x.y);
          pk[2] = (short)f2bf(x.z); pk[3] = (short)f2bf(x.w);
          pk[4] = (short)f2bf(y.x); pk[5] = (short)f2bf(y.y);
          pk[6] = (short)f2bf(y.z); pk[7] = (short)f2bf(y.w);
          *(bhalf8*)&lds[tile * 512 + l * 8] = pk;
        } else if constexpr (AF32 == 2) {
          const float* gf = (const float*)Av + (long)zz * sAb + (long)byy * 131072
                            + (long)(tile * 16 + lr) * 512 + k0 + lc * 8;
          float4 x = make_float4(0.f, 0.f, 0.f, 0.f), y = x;
#pragma unroll
          for (int c = 0; c < 4; ++c) {
            float4 a = *(const float4*)(gf + (long)c * 32768);
            float4 bq = *(const float4*)(gf + (long)c * 32768 + 4);
            x.x += a.x; x.y += a.y; x.z += a.z; x.w += a.w;
            y.x += bq.x; y.y += bq.y; y.z += bq.z; y.w += bq.w;
          }
          bhalf8 pk;
          pk[0] = (short)f2bf(x.x); pk[1] = (short)f2bf(x.y);
          pk[2] = (short)f2bf(x.z); pk[3] = (short)f2bf(x.w);
          pk[4] = (short)f2bf(y.x); pk[5] = (short)f2bf(y.y);
          pk[6] = (short)f2bf(y.z); pk[7] = (short)f2bf(y.w);
          *(bhalf8*)&lds[tile * 512 + l * 8] = pk;
        } else {
          gld16(Ag + (long)(tile * 16 + lr) * lda + k0 + lc * 8, &lds[tile * 512]);
        }
      } else {                                           // ---- B tile
        if constexpr (BF32 == 1) {
          const int ct = tile - NA;
          const float* gfB = Bf32 + (long)(koff + k0 + lc * 8) * ldbt + col0 + ct * 16 + lr;
          bhalf8 pk;
#pragma unroll
          for (int i2 = 0; i2 < 8; ++i2) pk[i2] = (short)f2bf(gfB[(long)i2 * ldbt]);
          *(bhalf8*)&lds[tile * 512 + l * 8] = pk;
        } else if constexpr (BF32 == 2) {
          const int ct = tile - NA;
          const float* src = (h ? Bf32b : Bf32) + (long)b * 1048576
                             + (long)(koff + k0 + lc * 8) * ldbt + col0 + ct * 16 + lr;
          bhalf8 pk;
#pragma unroll
          for (int i2 = 0; i2 < 8; ++i2) pk[i2] = (short)f2bf(src[(long)i2 * ldbt]);
          *(bhalf8*)&lds[tile * 512 + l * 8] = pk;
        } else {
          gld16(Bg + (long)((tile - NA) * 16 + lr) * ldbt + k0 + lc * 8, &lds[tile * 512]);
        }
      }
    }
    __syncthreads();
    bhalf8 af[FM], bf[FN];
#pragma unroll
    for (int i = 0; i < FM; ++i) af[i] = *(const bhalf8*)&lds[(wr * FM + i) * 512 + l * 8];
#pragma unroll
    for (int j = 0; j < FN; ++j) bf[j] = *(const bhalf8*)&lds[(NA + wc * FN + j) * 512 + l * 8];
#pragma unroll
    for (int i = 0; i < FM; ++i)
#pragma unroll
      for (int j = 0; j < FN; ++j)
        acc[i][j] = __builtin_amdgcn_mfma_f32_16x16x32_bf16(af[i], bf[j], acc[i][j], 0, 0, 0);
    __syncthreads();
  }

  if constexpr (CMODE == 3) {
    float (*tbuf)[65] = (float(*)[65])(smemc + NT * 1024);
#pragma unroll
    for (int fm = 0; fm < FM; ++fm) {
#pragma unroll
      for (int fn = 0; fn < FN; ++fn) {
        const int rg0 = row0 + wr * WM + fm * 16 + lc * 4;
        const int cg = col0 + wc * WN + fn * 16 + lr;
        const float bb = bias[cg];
#pragma unroll
        for (int jj = 0; jj < 4; ++jj) {
          const int rg = rg0 + jj;
          float vv = acc[fm][fn][jj] + bb;
          if (mpad[((long)(rg >> 11)) * (2048L * 2048) + (rg & 2047)] == 0) vv = -32768.f;
          __builtin_nontemporal_store(vv, (float*)Cout + (long)rg * ldc + cg);
          tbuf[rg - row0][cg] = vv;
        }
      }
    }
    __syncthreads();
    const int b0 = row0 >> 11, l0b = row0 & 2047;
    const int pp = t >> 2, li0 = (t & 3) * 16;
    float* dst = aux + ((long)b0 * 64 + pp) * 2048 + l0b + li0;
#pragma unroll
    for (int i = 0; i < 16; i += 4) {
      float4 o = make_float4(tbuf[li0 + i][pp],     tbuf[li0 + i + 1][pp],
                             tbuf[li0 + i + 2][pp], tbuf[li0 + i + 3][pp]);
      *(float4*)(dst + i) = o;
    }
  } else {
#pragma unroll
    for (int fm = 0; fm < FM; ++fm) {
#pragma unroll
      for (int fn = 0; fn < FN; ++fn) {
        const int rg0 = row0 + wr * WM + fm * 16 + lc * 4;
        const int cg = col0 + wc * WN + fn * 16 + lr;
        float bb = 0.f;
        if constexpr (CMODE == 4) {
          bb = (zz == 0) ? bias[cg] : ((const float*)mpad)[cg];
        } else {
          bb = bias ? bias[cg] : 0.f;
        }
#pragma unroll
        for (int jj = 0; jj < 4; ++jj) {
          const int rg = rg0 + jj;
          const float v = acc[fm][fn][jj] + bb;
          if constexpr (CMODE == 0) {
            ((float*)Cout)[b * sCb + h * sCh + cko + (long)rg * ldc + cg] = v;
          } else if constexpr (CMODE == 1) {
            ((unsigned short*)Cout)[b * sCb + h * sCh + (long)rg * ldc + cg] = f2bf(v);
          } else if constexpr (CMODE == 2) {
            ((unsigned short*)Cout)[(((long)(rg >> 6) * 8 + (cg >> 6)) * 64 + (cg & 63)) * 64 + (rg & 63)] = f2bf(v);
          } else if constexpr (CMODE == 4) {       // merged K/V-proj
            if (zz == 0)
              ((unsigned short*)Cout)[(long)rg * ldc + cg] = f2bf(v);
            else
              ((unsigned short*)Cout)[262144 + (((long)(rg >> 6) * 8 + (cg >> 6)) * 64 + (cg & 63)) * 64 + (rg & 63)] = f2bf(v);
          } else {                                 // CMODE 5: f32 nontemporal
            __builtin_nontemporal_store(v, (float*)Cout + b * sCb + h * sCh + cko + (long)rg * ldc + cg);
          }
        }
      }
    }
  }
}

template <int BM, int BN, int CMODE, int AF32, int KSPLIT>
__global__ __launch_bounds__(256)
void gemm_mfma(const void* __restrict__ Av, const unsigned short* __restrict__ BT,
               const float* __restrict__ bias, void* __restrict__ Cout,
               int K, int lda, int ldbt, int ldc, int HDIV,
               long sAb, long sAh, long sBb, long sBh, long sCb, long sCh, long sCk,
               const int* __restrict__ mpad, float* __restrict__ aux)
{
  constexpr int SM = (BM / 16 + BN / 16) * 1024 + (CMODE == 3 ? 16640 : 0);
  __shared__ __align__(16) char smem[SM];
  gemm_body<BM, BN, CMODE, AF32, KSPLIT, 0>(blockIdx.x, blockIdx.y, blockIdx.z, smem,
      Av, BT, bias, Cout, K, lda, ldbt, ldc, HDIV,
      sAb, sAh, sBb, sBh, sCb, sCh, sCk, mpad, aux, nullptr, nullptr);
}

// ---------------------------------------------------------------------------
// transpose body: in [R][Cd] f32 tile at (r0,c0) -> out [Cd][R] bf16
// ---------------------------------------------------------------------------
__device__ __forceinline__ void tr_body(float (*tile)[65], const float* __restrict__ in,
                                        unsigned short* __restrict__ out,
                                        int R, int Cd, int r0, int c0, int t)
{
  const int tr = t >> 4, tc4 = (t & 15) * 4;
#pragma unroll
  for (int pass = 0; pass < 4; ++pass) {
    int r = pass * 16 + tr;
    float4 v = *(const float4*)(in + (long)(r0 + r) * Cd + c0 + tc4);
    tile[r][tc4] = v.x; tile[r][tc4 + 1] = v.y; tile[r][tc4 + 2] = v.z; tile[r][tc4 + 3] = v.w;
  }
  __syncthreads();
#pragma unroll
  for (int pass = 0; pass < 4; ++pass) {
    int c = pass * 16 + tr;
    ushort4 o;
    o.x = f2bf(tile[tc4][c]);     o.y = f2bf(tile[tc4 + 1][c]);
    o.z = f2bf(tile[tc4 + 2][c]); o.w = f2bf(tile[tc4 + 3][c]);
    *(ushort4*)(out + (long)(c0 + c) * R + r0 + tc4) = o;
  }
}

// ---------------------------------------------------------------------------
// combo0: flat grid 512 blocks.
//  [0,256):   pScore GEMM (A=vx f32, B=Wp f32 strided) -> ps_out NT + pScoreT
//  [256,512): Wq/Wk/Wv/Wo transposes (4 x 64 tiles)
// ---------------------------------------------------------------------------
__global__ __launch_bounds__(256)
void combo0(const float* __restrict__ vx, const float* __restrict__ Wp,
            const float* __restrict__ bp, const int* __restrict__ maskPAD,
            float* __restrict__ ps_out, float* __restrict__ pScoreT,
            const float* __restrict__ Wq, const float* __restrict__ Wk,
            const float* __restrict__ Wv, const float* __restrict__ Wo,
            unsigned short* __restrict__ WqT, unsigned short* __restrict__ WkT,
            unsigned short* __restrict__ WvT, unsigned short* __restrict__ WoT)
{
  __shared__ __align__(16) char smem[24832];
  const int id = blockIdx.x;
  if (id < 256) {
    gemm_body<64, 64, 3, 1, 0, 1>(0, id, 0, smem,
        vx, nullptr, bp, ps_out, 512, 512, 64, 64, 1,
        0, 0, 0, 0, 0, 0, 0, maskPAD, pScoreT, Wp, nullptr);
  } else {
    const int r = id - 256;
    const int z = r >> 6, rem = r & 63;
    const float* in; unsigned short* out;
    switch (z) {
      case 0: in = Wq; out = WqT; break;
      case 1: in = Wk; out = WkT; break;
      case 2: in = Wv; out = WvT; break;
      default: in = Wo; out = WoT; break;
    }
    tr_body((float(*)[65])smem, in, out, 512, 512, (rem >> 3) * 64, (rem & 7) * 64, threadIdx.x);
  }
}

// ---------------------------------------------------------------------------
// kb body: (Kt,Bt) per (b,h,l,p) from an LDS-staged PS window.
// bx in [0,32): l0 = bx*64; by = b. Stages PSb[b, all p, l0-136..l0+199] clamped
// + slot 336 = PSb[b,p,2047]. Stride 338 shorts (conflict-free).
// ---------------------------------------------------------------------------
__device__ __forceinline__ void kb_body(int bx, int by, char* smemc,
    const unsigned short* __restrict__ PSb,
    const float* __restrict__ embK, const float* __restrict__ embB,
    ushort2* __restrict__ KB)
{
  const int L = 2048, STR = 338;
  unsigned short* psw = (unsigned short*)smemc;          // 64*338*2 = 43264 B
  float (*eKs)[8] = (float(*)[8])(smemc + 43264);
  float (*eBs)[8] = (float(*)[8])(smemc + 43264 + 512);
  const int t = threadIdx.x, b = by, l0 = bx * 64;
  if (t < 128) {
    int r = t >> 3, h = t & 7;
    eKs[r][h] = (r < 15) ? embK[r * 8 + h] : 0.f;
    eBs[r][h] = (r < 15) ? embB[r * 8 + h] : 0.f;
  }
  const int W0 = l0 - 136;
  const int w = t >> 6, ln = t & 63;
  for (int pr = w * 16; pr < w * 16 + 16; ++pr) {
    const unsigned short* src = PSb + ((long)b * 64 + pr) * 2048;
#pragma unroll
    for (int pass = 0; pass < 6; ++pass) {
      int j = pass * 64 + ln;
      if (j < 337) {
        int g = (j == 336) ? (L - 1) : (W0 + j);
        g = g < 0 ? 0 : (g > L - 1 ? L - 1 : g);
        psw[pr * STR + j] = src[g];
      }
    }
  }
  __syncthreads();
  const int p = ln;
  const int Btab[14] = {0,1,2,3,4,5,6,8,10,14,22,38,70,134};
  for (int step = 0; step < 16; ++step) {
    const int l = l0 + w * 16 + step;
    float U[15];
#pragma unroll
    for (int r = 0; r < 14; ++r) {
      int hi = l + Btab[r]; hi = hi > L - 1 ? L - 1 : hi;
      float u = bf2f(psw[p * STR + (hi - W0)]);
      const int lo = l - 1 - Btab[r];
      if (lo >= 0) u -= bf2f(psw[p * STR + (lo - W0)]);
      U[r] = u;
    }
    U[14] = bf2f(psw[p * STR + 336]);
    for (int h = 0; h < 8; ++h) {
      float Kt = 0.f, Bt = 0.f;
#pragma unroll
      for (int r = 0; r < 15; ++r) {
        Kt = fmaf(eKs[r][h] - eKs[r + 1][h], U[r], Kt);
        Bt = fmaf(eBs[r][h] - eBs[r + 1][h], U[r], Bt);
      }
      ushort2 o; o.x = f2bf(Kt); o.y = f2bf(Bt);
      KB[(((long)(b * 8 + h)) * L + l) * 64 + p] = o;
    }
  }
}

// combo1: blocks 0..511 -> split-K kxc/vxc GEMM partials (B direct from f32
// kx/vx via BF32=2, no transpose); 512..767 -> kb table. 3 blocks/CU.
__global__ __launch_bounds__(256)
void combo1(const unsigned short* __restrict__ pAbf,
            const float* __restrict__ kx, const float* __restrict__ vx,
            float* __restrict__ pbuf,
            const unsigned short* __restrict__ PSb,
            const float* __restrict__ embK, const float* __restrict__ embB,
            ushort2* __restrict__ KB)
{
  __shared__ __align__(16) char smem[44544];
  const int id = blockIdx.x;
  if (id < 512) {
    gemm_body<64, 64, 0, 0, 1, 2>(id & 7, (id >> 3) & 3, id >> 5, smem,
        pAbf, nullptr, nullptr, pbuf, 512, 2048, 512, 512, 2,
        131072, 0, 0, 0, 131072, 1048576, 32768, nullptr, nullptr, kx, vx);
  } else {
    const int r = id - 512;
    kb_body(r & 31, r >> 5, smem, PSb, embK, embB, KB);
  }
}

// combo2: blocks 0..63 -> merged K/V-proj (A = pbuf 4-sum); 64..575 -> Q-proj.
__global__ __launch_bounds__(256)
void combo2(const float* __restrict__ pbuf, const unsigned short* __restrict__ WkT,
            const float* __restrict__ bk, const float* __restrict__ bv,
            unsigned short* __restrict__ kp,
            const float* __restrict__ qx, const unsigned short* __restrict__ WqT,
            const float* __restrict__ bq, unsigned short* __restrict__ qbf)
{
  __shared__ __align__(16) char smem[16384];
  const int id = blockIdx.x;
  if (id < 64) {
    gemm_body<64, 128, 4, 2, 0, 0>(id & 3, (id >> 2) & 7, id >> 5, smem,
        pbuf, WkT, bk, kp, 512, 512, 512, 512, 1,
        1048576, 0, 262144, 0, 0, 0, 0, (const int*)bv, nullptr, nullptr, nullptr);
  } else {
    const int r = id - 64;
    gemm_body<128, 128, 1, 1, 0, 0>(r & 3, r >> 2, 0, smem,
        qx, WqT, bq, qbf, 512, 512, 512, 512, 1,
        0, 0, 0, 0, 0, 0, 0, nullptr, nullptr, nullptr, nullptr);
  }
}

// ---------------------------------------------------------------------------
// softmax over L per (b,p) + normalized inclusive prefix scan (coalesced).
// ---------------------------------------------------------------------------
__global__ __launch_bounds__(256)
void softmax_scan(const float* __restrict__ pScoreT,
                  unsigned short* __restrict__ PSb, unsigned short* __restrict__ pA_bf)
{
  __shared__ float red[256];
  const int p = blockIdx.x, b = blockIdx.y, t = threadIdx.x;
  const float* row = pScoreT + ((size_t)b * 64 + p) * 2048;
  float4 va = ((const float4*)row)[t * 2], vb = ((const float4*)row)[t * 2 + 1];
  float v[8] = {va.x, va.y, va.z, va.w, vb.x, vb.y, vb.z, vb.w};
  float mx = v[0];
#pragma unroll
  for (int i = 1; i < 8; ++i) mx = fmaxf(mx, v[i]);
  red[t] = mx; __syncthreads();
  for (int s = 128; s > 0; s >>= 1) { if (t < s) red[t] = fmaxf(red[t], red[t + s]); __syncthreads(); }
  float m = red[0]; __syncthreads();
  float e[8]; float s = 0.f;
#pragma unroll
  for (int i = 0; i < 8; ++i) { e[i] = expf(v[i] - m); s += e[i]; }
  red[t] = s; __syncthreads();
  for (int o = 1; o < 256; o <<= 1) {
    float x = (t >= o) ? red[t - o] : 0.f;
    __syncthreads(); red[t] += x; __syncthreads();
  }
  float inv = 1.0f / red[255];
  float run = red[t] - s;
  size_t base = ((size_t)b * 64 + p) * 2048 + (size_t)t * 8;
#pragma unroll
  for (int i = 0; i < 8; ++i) {
    run += e[i];
    PSb[base + i] = f2bf(run * inv);
    pA_bf[base + i] = f2bf(e[i] * inv);
  }
}

// ---------------------------------------------------------------------------
// Fused attention with XCD-bijective block swizzle; KB prefetched to registers.
// ---------------------------------------------------------------------------
__global__ __launch_bounds__(256)
void attn_fused(const unsigned short* __restrict__ qb,   // [B,L,512] bf16
                const unsigned short* __restrict__ kp,   // [B,64,512] bf16
                const unsigned short* __restrict__ vpT,  // [B,H,64,64] bf16
                const ushort2* __restrict__ KB,          // [B,H,L,64] (Kt,Bt)
                float* __restrict__ sc_out,              // [B,H,L,64] f32
                unsigned short* __restrict__ zpre)       // [B,L,512] bf16
{
  const int L = 2048;
  __shared__ __align__(16) unsigned short stg[24 * 512]; // q 0..15, kp 16..23; V reuses 0..7
  unsigned short* qkb = &stg[8 * 512];                   // qk/alpha overlays tiles 8..23
  const int t = threadIdx.x, l = t & 63, w = t >> 6, lr = l & 15, lc = l >> 4;
  const int flat = blockIdx.y * 16 + blockIdx.x;
  const int swz = (flat & 7) * 128 + (flat >> 3);
  const int z = swz >> 4, b = z >> 3, h = z & 7;
  const int l0 = (swz & 15) * 128;
  const unsigned short* Ag = qb + ((long)(b * L + l0)) * 512 + h * 64;
  const unsigned short* Bg = kp + (long)b * 64 * 512 + h * 64;
#pragma unroll
  for (int i = 0; i < 6; ++i) {                          // stage q (16 tiles) + kp (8)
    const int tile = w + i * 4;
    const unsigned short* g;
    if (tile < 16) { int rt = tile >> 1, ks = tile & 1; g = Ag + (long)(rt * 16 + lr) * 512 + ks * 32 + lc * 8; }
    else { int j = tile - 16; int rt = j >> 1, ks = j & 1; g = Bg + (long)(rt * 16 + lr) * 512 + ks * 32 + lc * 8; }
    gld16(g, &stg[tile * 512]);
  }
  const ushort2* kbb = KB + (((long)(b * 8 + h)) * L + l0) * 64 + l;
  unsigned int kbreg[32];
#pragma unroll
  for (int i = 0; i < 32; ++i)
    kbreg[i] = *(const unsigned int*)(kbb + ((long)(w * 32 + i)) * 64);
  __syncthreads();
  // ---- phase 1: QK MFMA (2x2 waves, WM=64, WN=32, FM=4, FN=2)
  const int wr = w >> 1, wc = w & 1;
  fx4 acc[4][2];
#pragma unroll
  for (int i = 0; i < 4; ++i)
#pragma unroll
    for (int j = 0; j < 2; ++j) acc[i][j] = fx4{0.f, 0.f, 0.f, 0.f};
#pragma unroll
  for (int ks = 0; ks < 2; ++ks) {
    bhalf8 af[4], bf[2];
#pragma unroll
    for (int i = 0; i < 4; ++i) af[i] = *(const bhalf8*)&stg[((wr * 4 + i) * 2 + ks) * 512 + l * 8];
#pragma unroll
    for (int j = 0; j < 2; ++j) bf[j] = *(const bhalf8*)&stg[(16 + (wc * 2 + j) * 2 + ks) * 512 + l * 8];
#pragma unroll
    for (int i = 0; i < 4; ++i)
#pragma unroll
      for (int j = 0; j < 2; ++j)
        acc[i][j] = __builtin_amdgcn_mfma_f32_16x16x32_bf16(af[i], bf[j], acc[i][j], 0, 0, 0);
  }
  __syncthreads();                                       // q/kp tiles dead -> qk overlays
#pragma unroll
  for (int fm = 0; fm < 4; ++fm)
#pragma unroll
    for (int fn = 0; fn < 2; ++fn)
#pragma unroll
      for (int jj = 0; jj < 4; ++jj) {
        const int row = wr * 64 + fm * 16 + lc * 4 + jj;
        const int col = wc * 32 + fn * 16 + lr;
        *(unsigned short*)((char*)qkb + ((row * 128 + col * 2) ^ ((row & 7) << 4))) = f2bf(acc[fm][fn][jj]);
      }
  __syncthreads();
  // stage V (8 tiles into stg 0..7), overlapping phase 2
  {
    const unsigned short* Vg = vpT + ((long)(b * 8 + h)) * 64 * 64;
#pragma unroll
    for (int i = 0; i < 2; ++i) {
      const int tile = w + i * 4, rt = tile >> 1, ks = tile & 1;
      gld16(Vg + (long)(rt * 16 + lr) * 64 + ks * 32 + lc * 8, &stg[tile * 512]);
    }
  }
  // ---- phase 2: scores from KB regs + softmax_P (wave w rows w*32..+31, lane = p)
  const int p = l;
  float* scb = sc_out + ((long)(b * 8 + h) * L + l0) * 64 + p;
#pragma unroll
  for (int c = 0; c < 8; ++c) {
    const int rbase = w * 32 + c * 4;
    float sv[4];
#pragma unroll
    for (int il = 0; il < 4; ++il) {
      const int row = rbase + il;
      const unsigned int kbw = kbreg[c * 4 + il];
      const float qkv = bf2f(*(const unsigned short*)((const char*)qkb + ((row * 128 + p * 2) ^ ((row & 7) << 4))));
      sv[il] = qkv * 0.125f * bf2f((unsigned short)(kbw & 0xffffu)) + bf2f((unsigned short)(kbw >> 16));
      __builtin_nontemporal_store(sv[il], scb + (long)row * 64);
    }
    float mx[4] = {sv[0], sv[1], sv[2], sv[3]};
#pragma unroll
    for (int o = 32; o > 0; o >>= 1)
#pragma unroll
      for (int il = 0; il < 4; ++il) mx[il] = fmaxf(mx[il], __shfl_xor(mx[il], o, 64));
    float ex[4], sm[4];
#pragma unroll
    for (int il = 0; il < 4; ++il) { ex[il] = __expf(sv[il] - mx[il]); sm[il] = ex[il]; }
#pragma unroll
    for (int o = 32; o > 0; o >>= 1)
#pragma unroll
      for (int il = 0; il < 4; ++il) sm[il] += __shfl_xor(sm[il], o, 64);
#pragma unroll
    for (int il = 0; il < 4; ++il) {
      const int row = rbase + il;
      *(unsigned short*)((char*)qkb + ((row * 128 + p * 2) ^ ((row & 7) << 4))) = f2bf(ex[il] / sm[il]);
    }
  }
  __syncthreads();
  // ---- phase 3: PV MFMA (A = alpha LDS swizzled, B = V tiles 0..7)
  fx4 a2[4][2];
#pragma unroll
  for (int i = 0; i < 4; ++i)
#pragma unroll
    for (int j = 0; j < 2; ++j) a2[i][j] = fx4{0.f, 0.f, 0.f, 0.f};
#pragma unroll
  for (int ks = 0; ks < 2; ++ks) {
    bhalf8 paf[4], pvf[2];
#pragma unroll
    for (int i = 0; i < 4; ++i) {
      const int row = (wr * 4 + i) * 16 + lr;
      paf[i] = *(const bhalf8*)((const char*)qkb + ((row * 128 + ks * 64 + lc * 16) ^ ((row & 7) << 4)));
    }
#pragma unroll
    for (int j = 0; j < 2; ++j)
      pvf[j] = *(const bhalf8*)&stg[(((wc * 2 + j) * 2 + ks) * 512) + l * 8];
#pragma unroll
    for (int i = 0; i < 4; ++i)
#pragma unroll
      for (int j = 0; j < 2; ++j)
        a2[i][j] = __builtin_amdgcn_mfma_f32_16x16x32_bf16(paf[i], pvf[j], a2[i][j], 0, 0, 0);
  }
#pragma unroll
  for (int fm = 0; fm < 4; ++fm)
#pragma unroll
    for (int fn = 0; fn < 2; ++fn)
#pragma unroll
      for (int jj = 0; jj < 4; ++jj) {
        const int row = wr * 64 + fm * 16 + lc * 4 + jj;
        const int col = wc * 32 + fn * 16 + lr;
        zpre[((long)(b * L + l0 + row)) * 512 + h * 64 + col] = f2bf(a2[fm][fn][jj]);
      }
}

// ---------------------------------------------------------------------------
extern "C" void kernel_launch(void* const* d_in, const int* in_sizes, int n_in,
                              void* d_out, int out_size, void* d_ws, size_t ws_size,
                              hipStream_t stream)
{
  const int B = 8, L = 2048, C = 512, P = 64;
  const float* qx = (const float*)d_in[0];
  const float* kx = (const float*)d_in[1];
  const float* vx = (const float*)d_in[2];
  const int* maskPAD = (const int*)d_in[3];
  const float* Wp = (const float*)d_in[4];
  const float* bp = (const float*)d_in[5];
  const float* Wq = (const float*)d_in[6];
  const float* bq = (const float*)d_in[7];
  const float* Wk = (const float*)d_in[8];
  const float* bk = (const float*)d_in[9];
  const float* Wv = (const float*)d_in[10];
  const float* bv = (const float*)d_in[11];
  const float* Wo = (const float*)d_in[12];
  const float* bo = (const float*)d_in[13];
  const float* embK = (const float*)d_in[14];
  const float* embB = (const float*)d_in[15];

  float* z_out  = (float*)d_out;                         // [B,L,C]
  float* ps_out = z_out + (size_t)B * L * C;             // [B,L,P]
  float* sc_out = ps_out + (size_t)B * L * P;            // [B,H,L,P]

  char* w8 = (char*)d_ws;
  size_t o = 0;
  auto take = [&](size_t n) { char* r = w8 + o; o += n; return r; };
  unsigned short* R_A  = (unsigned short*)take(16777216); // zpre [B,L,512]
  unsigned short* R_B  = (unsigned short*)take(16777216); // q_bf [B,L,512]
  unsigned short* WqT  = (unsigned short*)take(524288);
  unsigned short* WkT  = (unsigned short*)take(524288);
  unsigned short* WvT  = (unsigned short*)take(524288);
  unsigned short* WoT  = (unsigned short*)take(524288);
  float* pScoreT       = (float*)take(4194304);          // [B,P,L] f32 (masked)
  unsigned short* PSb  = (unsigned short*)take(2097152); // [B,P,L] bf16 prefix
  unsigned short* pAbf = (unsigned short*)take(2097152); // [B,P,L] bf16
  float* pbuf          = (float*)take(8388608);          // [2][8][4][32768]
  unsigned short* kp   = (unsigned short*)take(1048576); // kp then vpT (contiguous)
  ushort2* KB          = (ushort2*)take(33554432);       // [B,H,L,64] (Kt,Bt) bf16

  // 1) combo0: pScore GEMM (input-only) || weight transposes
  combo0<<<dim3(512), 256, 0, stream>>>(
      vx, Wp, bp, maskPAD, ps_out, pScoreT,
      Wq, Wk, Wv, Wo, WqT, WkT, WvT, WoT);
  // 2) softmax_L + prefix scan -> PSb bf16, pAbf bf16
  softmax_scan<<<dim3(P, B), 256, 0, stream>>>(pScoreT, PSb, pAbf);
  // 3) combo1: split-K kxc/vxc partials (B direct from kx/vx) || KB table
  combo1<<<dim3(768), 256, 0, stream>>>(pAbf, kx, vx, pbuf, PSb, embK, embB, KB);
  // 4) combo2: merged K/V-proj from pbuf (64 blocks) || Q-proj (512 blocks)
  combo2<<<dim3(576), 256, 0, stream>>>(pbuf, WkT, bk, bv, kp, qx, WqT, bq, R_B);
  // 5) fused attention: scores (NT f32) + softmax + PV -> zpre
  attn_fused<<<dim3(16, 64), 256, 0, stream>>>(
      R_B, kp, kp + 262144, KB, sc_out, R_A);
  // 6) z = zpre @ Wo + bo (NT f32)
  gemm_mfma<128, 128, 5, 0, 0><<<dim3(4, 128, 1), 256, 0, stream>>>(
      R_A, WoT, bo, z_out, 512, 512, 512, 512, 1, 0, 0, 0, 0, 0, 0, 0, nullptr, nullptr);
}